// Round 3
// baseline (320.759 us; speedup 1.0000x reference)
//
#include <hip/hip_runtime.h>
#include <hip/hip_bf16.h>

// GCN_simple: B=512 graphs x 128 nodes, FEAT=HID=512, OUT=10.
// R11: SPLIT design. The fused 1-block/CU kernel is phase-locked by
// block-wide barriers (MfmaUtil capped ~24%). Split into two GEMM kernels
// (128x256 tile, 512 threads, 56KB LDS -> 2 independent blocks/CU) with H1
// round-tripped through L3/HBM (64MB bf16). Graph == M-tile, so g0 fixup and
// mean-pool are block-local. XCD-chunked block swizzle for A/B L2 locality.
// Fallback: if ws_size can't hold H1, run the verified R9 fused path.
// Dispatches: prep -> gemm1 -> gemm2 -> final_out (split) | prep -> fused (fb).

typedef __attribute__((ext_vector_type(8))) short short8;
typedef __attribute__((ext_vector_type(4))) float f32x4;
typedef __attribute__((ext_vector_type(2))) unsigned int uint2v;
typedef __attribute__((ext_vector_type(4))) unsigned int uint4v;

#define AS_G __attribute__((address_space(1)))
#define AS_L __attribute__((address_space(3)))

__device__ __forceinline__ void gload_lds16(const void* g, void* l) {
  __builtin_amdgcn_global_load_lds((const AS_G void*)g, (AS_L void*)l, 16, 0, 0);
}

// RNE fp32->bf16 (finite), packed: b -> high 16, a -> low 16.
__device__ __forceinline__ unsigned int pack2_bf16(float a, float b) {
  unsigned int ua = __float_as_uint(a);
  unsigned int ub = __float_as_uint(b);
  ua += 0x7FFFu + ((ua >> 16) & 1u);
  ub += 0x7FFFu + ((ub >> 16) & 1u);
  return (ua >> 16) | (ub & 0xFFFF0000u);
}

__device__ __forceinline__ unsigned short bf16_rne(float a) {
  unsigned int ua = __float_as_uint(a);
  ua += 0x7FFFu + ((ua >> 16) & 1u);
  return (unsigned short)(ua >> 16);
}

// ---------------------------------------------------------------------------
// gemm1: H1 = relu(agg(x @ W1) + b1), bf16 out.  Grid 1024 = 512 graphs x 2
// col-halves. Block 512 thr / 8 waves, tile 128x256, K=512 in 16 steps of 32.
// A (x fp32) load+pack+ds_write dbuf; B (W1t bf16) gload_lds dbuf.
// ---------------------------------------------------------------------------
__global__ __launch_bounds__(512, 4) void gemm1(
    const float* __restrict__ x,
    const __hip_bfloat16* __restrict__ W1t,   // [n][k] bf16
    const float* __restrict__ b1,
    unsigned short* __restrict__ H1)          // [65536][512] bf16
{
  // LDS: A dbuf 2x4096 elems [0,8192); B dbuf 2x8192 [8192,24576); scratch f32
  __shared__ __align__(16) __hip_bfloat16 smem[26368];

  const int t    = threadIdx.x;
  const int orig = blockIdx.x;
  // XCD-chunked bijective swizzle (1024 % 8 == 0)
  const int wgid = (orig & 7) * 128 + (orig >> 3);
  const int g    = wgid >> 1;          // graph / M-tile
  const int nb   = wgid & 1;           // col half (256 cols)

  const int wave = t >> 6;
  const int l    = t & 63;
  const int q    = l >> 4;
  const int r16  = l & 15;
  const int wm   = (wave & 1) * 64;
  const int wn   = (wave >> 1) * 64;   // 0,64,128,192

  // A staging: thread (arow=t>>2, cc=t&3) packs 8 f32 -> one b128 chunk
  const int arow = t >> 2;
  const int cc   = t & 3;
  const float* gx = x + ((size_t)g * 128 + arow) * 512 + cc * 8;
  const int awoff = arow * 32 + ((cc ^ ((arow >> 1) & 3)) << 3);  // elems

  // B staging: 2 issues; issue e covers u = e*512 + t
  const int nrow0 = t >> 2;            // e=0
  const int nrow1 = (512 + t) >> 2;    // e=1
  const int slot  = t & 3;
  const __hip_bfloat16* gb0 = W1t + (size_t)(nb * 256 + nrow0) * 512 +
                              ((slot ^ ((nrow0 >> 1) & 3)) << 3);
  const __hip_bfloat16* gb1 = W1t + (size_t)(nb * 256 + nrow1) * 512 +
                              ((slot ^ ((nrow1 >> 1) & 3)) << 3);

  f32x4 acc[4][4];
#pragma unroll
  for (int i = 0; i < 4; ++i)
#pragma unroll
    for (int j = 0; j < 4; ++j)
      acc[i][j] = (f32x4)0.0f;

  // prologue: stage kt=0 into buf 0
  {
    f32x4 a0 = *(const f32x4*)(const void*)gx;
    f32x4 a1 = *(const f32x4*)(const void*)(gx + 4);
    gload_lds16(gb0, smem + 8192 + wave * 512);
    gload_lds16(gb1, smem + 8192 + 4096 + wave * 512);
    uint4v w;
    w[0] = pack2_bf16(a0[0], a0[1]);
    w[1] = pack2_bf16(a0[2], a0[3]);
    w[2] = pack2_bf16(a1[0], a1[1]);
    w[3] = pack2_bf16(a1[2], a1[3]);
    *(uint4v*)(void*)(smem + awoff) = w;
  }

  for (int kt = 0; kt < 16; ++kt) {
    const int cur = kt & 1;
    const int nxt = cur ^ 1;
    __syncthreads();

    f32x4 aN0, aN1;
    if (kt < 15) {
      const int ko = (kt + 1) * 32;
      aN0 = *(const f32x4*)(const void*)(gx + ko);
      aN1 = *(const f32x4*)(const void*)(gx + ko + 4);
      gload_lds16(gb0 + ko, smem + 8192 + nxt * 8192 + wave * 512);
      gload_lds16(gb1 + ko, smem + 8192 + nxt * 8192 + 4096 + wave * 512);
    }

    short8 af[4], bfr[4];
#pragma unroll
    for (int i = 0; i < 4; ++i) {
      const int row = wm + i * 16 + r16;
      const int c   = (q ^ ((row >> 1) & 3)) << 3;
      af[i] = *(const short8*)(const void*)(smem + cur * 4096 + row * 32 + c);
    }
#pragma unroll
    for (int j = 0; j < 4; ++j) {
      const int row = wn + j * 16 + r16;
      const int c   = (q ^ ((row >> 1) & 3)) << 3;
      bfr[j] = *(const short8*)(const void*)(smem + 8192 + cur * 8192 + row * 32 + c);
    }
    __builtin_amdgcn_s_setprio(1);
#pragma unroll
    for (int i = 0; i < 4; ++i)
#pragma unroll
      for (int j = 0; j < 4; ++j)
        acc[i][j] = __builtin_amdgcn_mfma_f32_16x16x32_bf16(af[i], bfr[j], acc[i][j], 0, 0, 0);
    __builtin_amdgcn_s_setprio(0);

    if (kt < 15) {
      uint4v w;
      w[0] = pack2_bf16(aN0[0], aN0[1]);
      w[1] = pack2_bf16(aN0[2], aN0[3]);
      w[2] = pack2_bf16(aN1[0], aN1[1]);
      w[3] = pack2_bf16(aN1[2], aN1[3]);
      *(uint4v*)(void*)(smem + nxt * 4096 + awoff) = w;
    }
  }

  float* redf = (float*)(smem + 24576);   // 8*64 f32
  float* Sbuf = (float*)(smem + 25600);   // 256 f32

  if (g == 0) {
    // column sums over all 128 rows (this block owns all of graph 0's rows)
    float sj[4];
#pragma unroll
    for (int j = 0; j < 4; ++j) {
      float a = 0.0f;
#pragma unroll
      for (int i = 0; i < 4; ++i)
#pragma unroll
        for (int r = 0; r < 4; ++r)
          a += acc[i][j][r];
      a += __shfl_xor(a, 16, 64);
      a += __shfl_xor(a, 32, 64);
      sj[j] = a;
    }
    __syncthreads();
    if (q == 0) {
#pragma unroll
      for (int j = 0; j < 4; ++j) redf[wave * 64 + j * 16 + r16] = sj[j];
    }
    __syncthreads();
    if (t < 256)
      Sbuf[t] = redf[(2 * (t >> 6)) * 64 + (t & 63)] +
                redf[(2 * (t >> 6) + 1) * 64 + (t & 63)];
    __syncthreads();
#pragma unroll
    for (int j = 0; j < 4; ++j) {
      const int col = wn + j * 16 + r16;
      const float bv = b1[nb * 256 + col];
      const float Sv = Sbuf[col];
#pragma unroll
      for (int i = 0; i < 4; ++i)
#pragma unroll
        for (int r = 0; r < 4; ++r) {
          const int row = wm + i * 16 + q * 4 + r;
          const float v = fmaxf((Sv + acc[i][j][r]) * (1.0f / 129.0f) + bv, 0.0f);
          const float o = __shfl_xor(v, 1, 64);
          if ((r16 & 1) == 0)
            *(unsigned int*)(void*)(H1 + (size_t)(g * 128 + row) * 512 + nb * 256 + col) =
                pack2_bf16(v, o);
        }
    }
  } else {
#pragma unroll
    for (int j = 0; j < 4; ++j) {
      const int col = wn + j * 16 + r16;
      const float bv = b1[nb * 256 + col];
#pragma unroll
      for (int i = 0; i < 4; ++i)
#pragma unroll
        for (int r = 0; r < 4; ++r) {
          const int row = wm + i * 16 + q * 4 + r;
          const float v = fmaxf(acc[i][j][r] + bv, 0.0f);
          const float o = __shfl_xor(v, 1, 64);
          if ((r16 & 1) == 0)
            *(unsigned int*)(void*)(H1 + (size_t)(g * 128 + row) * 512 + nb * 256 + col) =
                pack2_bf16(v, o);
        }
    }
  }
}

// ---------------------------------------------------------------------------
// gemm2: C2 = H1 @ W2; P[g][c] = (1/128) * sum_rows relu(agg(C2) + b2).
// Same geometry as gemm1; A (H1 bf16) staged purely via gload_lds.
// ---------------------------------------------------------------------------
__global__ __launch_bounds__(512, 4) void gemm2(
    const unsigned short* __restrict__ H1,    // [65536][512] bf16
    const __hip_bfloat16* __restrict__ W2t,   // [n][k] bf16
    const float* __restrict__ b2,
    float* __restrict__ P)                    // [512][512] f32 (mean-pooled)
{
  __shared__ __align__(16) __hip_bfloat16 smem[26368];

  const int t    = threadIdx.x;
  const int orig = blockIdx.x;
  const int wgid = (orig & 7) * 128 + (orig >> 3);
  const int g    = wgid >> 1;
  const int nb   = wgid & 1;

  const int wave = t >> 6;
  const int l    = t & 63;
  const int q    = l >> 4;
  const int r16  = l & 15;
  const int wm   = (wave & 1) * 64;
  const int wn   = (wave >> 1) * 64;

  // A staging (1 gload_lds/thread): u = t -> (arow = t>>2, slot = t&3)
  const int arow = t >> 2;
  const int slot = t & 3;
  const unsigned short* gaA = H1 + (size_t)(g * 128 + arow) * 512 +
                              ((slot ^ ((arow >> 1) & 3)) << 3);
  // B staging (2 issues)
  const int nrow0 = t >> 2;
  const int nrow1 = (512 + t) >> 2;
  const __hip_bfloat16* gb0 = W2t + (size_t)(nb * 256 + nrow0) * 512 +
                              ((slot ^ ((nrow0 >> 1) & 3)) << 3);
  const __hip_bfloat16* gb1 = W2t + (size_t)(nb * 256 + nrow1) * 512 +
                              ((slot ^ ((nrow1 >> 1) & 3)) << 3);

  f32x4 acc[4][4];
#pragma unroll
  for (int i = 0; i < 4; ++i)
#pragma unroll
    for (int j = 0; j < 4; ++j)
      acc[i][j] = (f32x4)0.0f;

  // prologue: stage kt=0
  gload_lds16(gaA, smem + wave * 512);
  gload_lds16(gb0, smem + 8192 + wave * 512);
  gload_lds16(gb1, smem + 8192 + 4096 + wave * 512);

  for (int kt = 0; kt < 16; ++kt) {
    const int cur = kt & 1;
    const int nxt = cur ^ 1;
    __syncthreads();

    if (kt < 15) {
      const int ko = (kt + 1) * 32;
      gload_lds16(gaA + ko, smem + nxt * 4096 + wave * 512);
      gload_lds16(gb0 + ko, smem + 8192 + nxt * 8192 + wave * 512);
      gload_lds16(gb1 + ko, smem + 8192 + nxt * 8192 + 4096 + wave * 512);
    }

    short8 af[4], bfr[4];
#pragma unroll
    for (int i = 0; i < 4; ++i) {
      const int row = wm + i * 16 + r16;
      const int c   = (q ^ ((row >> 1) & 3)) << 3;
      af[i] = *(const short8*)(const void*)(smem + cur * 4096 + row * 32 + c);
    }
#pragma unroll
    for (int j = 0; j < 4; ++j) {
      const int row = wn + j * 16 + r16;
      const int c   = (q ^ ((row >> 1) & 3)) << 3;
      bfr[j] = *(const short8*)(const void*)(smem + 8192 + cur * 8192 + row * 32 + c);
    }
    __builtin_amdgcn_s_setprio(1);
#pragma unroll
    for (int i = 0; i < 4; ++i)
#pragma unroll
      for (int j = 0; j < 4; ++j)
        acc[i][j] = __builtin_amdgcn_mfma_f32_16x16x32_bf16(af[i], bfr[j], acc[i][j], 0, 0, 0);
    __builtin_amdgcn_s_setprio(0);
  }

  float* redf = (float*)(smem + 24576);   // 8*64 f32
  float* Sbuf = (float*)(smem + 25600);   // 256 f32

  float pj[4];
  if (g == 0) {
    float sj[4];
#pragma unroll
    for (int j = 0; j < 4; ++j) {
      float a = 0.0f;
#pragma unroll
      for (int i = 0; i < 4; ++i)
#pragma unroll
        for (int r = 0; r < 4; ++r)
          a += acc[i][j][r];
      a += __shfl_xor(a, 16, 64);
      a += __shfl_xor(a, 32, 64);
      sj[j] = a;
    }
    __syncthreads();
    if (q == 0) {
#pragma unroll
      for (int j = 0; j < 4; ++j) redf[wave * 64 + j * 16 + r16] = sj[j];
    }
    __syncthreads();
    if (t < 256)
      Sbuf[t] = redf[(2 * (t >> 6)) * 64 + (t & 63)] +
                redf[(2 * (t >> 6) + 1) * 64 + (t & 63)];
    __syncthreads();
#pragma unroll
    for (int j = 0; j < 4; ++j) {
      const int col = wn + j * 16 + r16;
      const float bv = b2[nb * 256 + col];
      const float Sv = Sbuf[col];
      float a = 0.0f;
#pragma unroll
      for (int i = 0; i < 4; ++i)
#pragma unroll
        for (int r = 0; r < 4; ++r)
          a += fmaxf((Sv + acc[i][j][r]) * (1.0f / 129.0f) + bv, 0.0f);
      a += __shfl_xor(a, 16, 64);
      a += __shfl_xor(a, 32, 64);
      pj[j] = a;
    }
    __syncthreads();   // Sbuf/redf reads done before redf reuse below
  } else {
#pragma unroll
    for (int j = 0; j < 4; ++j) {
      const float bv = b2[nb * 256 + wn + j * 16 + r16];
      float a = 0.0f;
#pragma unroll
      for (int i = 0; i < 4; ++i)
#pragma unroll
        for (int r = 0; r < 4; ++r)
          a += fmaxf(acc[i][j][r] + bv, 0.0f);
      a += __shfl_xor(a, 16, 64);
      a += __shfl_xor(a, 32, 64);
      pj[j] = a;
    }
    __syncthreads();
  }
  if (q == 0) {
#pragma unroll
    for (int j = 0; j < 4; ++j) redf[wave * 64 + j * 16 + r16] = pj[j];
  }
  __syncthreads();
  if (t < 256)
    P[(size_t)g * 512 + nb * 256 + t] =
        (redf[(2 * (t >> 6)) * 64 + (t & 63)] +
         redf[(2 * (t >> 6) + 1) * 64 + (t & 63)]) * (1.0f / 128.0f);
}

// out[m][:] = P[m][:] @ Wf + bfv
__global__ void final_out(const float* __restrict__ P,
                          const float* __restrict__ Wf,
                          const float* __restrict__ bfv,
                          float* __restrict__ out) {
  const int m = blockIdx.x;
  const int l = threadIdx.x;
  float acc[10];
#pragma unroll
  for (int o = 0; o < 10; ++o) acc[o] = 0.0f;
  for (int c = l; c < 512; c += 64) {
    const float p = P[m * 512 + c];
#pragma unroll
    for (int o = 0; o < 10; ++o) acc[o] += p * Wf[c * 10 + o];
  }
#pragma unroll
  for (int off = 32; off; off >>= 1)
#pragma unroll
    for (int o = 0; o < 10; ++o) acc[o] += __shfl_down(acc[o], off, 64);
  if (l == 0) {
#pragma unroll
    for (int o = 0; o < 10; ++o) out[m * 10 + o] = acc[o] + bfv[o];
  }
}

// ===========================================================================
// R9 fused kernel (verified) — fallback when workspace can't hold H1.
// ===========================================================================
__global__ __launch_bounds__(1024) void fused_gcn(
    const float* __restrict__ x,
    const __hip_bfloat16* __restrict__ W1t,
    const __hip_bfloat16* __restrict__ W2t,
    const float* __restrict__ b1,
    const float* __restrict__ b2,
    const float* __restrict__ Wf,
    const float* __restrict__ bfv,
    float* __restrict__ out)
{
  __shared__ __align__(16) __hip_bfloat16 smem[81920];

  const int t  = threadIdx.x;
  const int g  = blockIdx.x;
  const int wave = t >> 6;
  const int l    = t & 63;
  const int q    = l >> 4;
  const int r16  = l & 15;
  const int wm   = (wave & 1) * 64;
  const int wn   = (wave >> 1) * 64;

  const int arow = t >> 3;
  const int kq   = t & 7;
  const float* ga = x + ((size_t)g * 128 + arow) * 512 + kq * 4;
  const int awoff = arow * 32 + (((kq >> 1) ^ ((arow >> 1) & 3)) << 3) + (kq & 1) * 4;

  const int brow = t >> 2;
  const int bgc  = (t & 3) ^ ((brow >> 1) & 3);
  const size_t boff = (size_t)brow * 512 + bgc * 8;
  const __hip_bfloat16* g1b0 = W1t + boff;
  const __hip_bfloat16* g1b1 = g1b0 + (size_t)256 * 512;

  f32x4 acc[4][4];
#pragma unroll
  for (int i = 0; i < 4; ++i)
#pragma unroll
    for (int j = 0; j < 4; ++j)
      acc[i][j] = (f32x4)0.0f;

  {
    f32x4 a0 = *(const f32x4*)(const void*)ga;
    gload_lds16(g1b0, smem + 49152 + wave * 512);
    gload_lds16(g1b1, smem + 49152 + 8192 + wave * 512);
    uint2v w;
    w[0] = pack2_bf16(a0[0], a0[1]);
    w[1] = pack2_bf16(a0[2], a0[3]);
    *(uint2v*)(void*)(smem + awoff) = w;
  }
  for (int kt = 0; kt < 16; ++kt) {
    const int cur = kt & 1;
    const int nxt = cur ^ 1;
    __syncthreads();

    f32x4 aN;
    if (kt < 15) {
      const int ko = (kt + 1) * 32;
      aN = *(const f32x4*)(const void*)(ga + ko);
      gload_lds16(g1b0 + ko, smem + 49152 + nxt * 16384 + wave * 512);
      gload_lds16(g1b1 + ko, smem + 49152 + nxt * 16384 + 8192 + wave * 512);
    }

    short8 af[4], bfr[4];
#pragma unroll
    for (int i = 0; i < 4; ++i) {
      const int row = wm + i * 16 + r16;
      const int c   = (q ^ ((row >> 1) & 3)) << 3;
      af[i] = *(const short8*)(const void*)(smem + cur * 4096 + row * 32 + c);
    }
#pragma unroll
    for (int j = 0; j < 4; ++j) {
      const int row = wn + j * 16 + r16;
      const int c   = (q ^ ((row >> 1) & 3)) << 3;
      bfr[j] = *(const short8*)(const void*)(smem + 49152 + cur * 16384 + row * 32 + c);
    }
#pragma unroll
    for (int i = 0; i < 4; ++i)
#pragma unroll
      for (int j = 0; j < 4; ++j)
        acc[i][j] = __builtin_amdgcn_mfma_f32_16x16x32_bf16(af[i], bfr[j], acc[i][j], 0, 0, 0);

    if (kt < 15) {
      uint2v w;
      w[0] = pack2_bf16(aN[0], aN[1]);
      w[1] = pack2_bf16(aN[2], aN[3]);
      *(uint2v*)(void*)(smem + nxt * 4096 + awoff) = w;
    }
  }
  __syncthreads();

  const __hip_bfloat16* g2b0 = W2t + boff;
  const __hip_bfloat16* g2b1 = g2b0 + (size_t)256 * 512;
  gload_lds16(g2b0, smem + 65536 + wave * 512);

  float* redf = (float*)(smem + 73728);
  float* Sbuf = (float*)(smem + 75776);

  if (g == 0) {
    float sj[4];
#pragma unroll
    for (int j = 0; j < 4; ++j) {
      float a = 0.0f;
#pragma unroll
      for (int i = 0; i < 4; ++i)
#pragma unroll
        for (int r = 0; r < 4; ++r)
          a += acc[i][j][r];
      a += __shfl_xor(a, 16, 64);
      a += __shfl_xor(a, 32, 64);
      sj[j] = a;
    }
    if (q == 0) {
#pragma unroll
      for (int j = 0; j < 4; ++j) redf[wave * 64 + j * 16 + r16] = sj[j];
    }
    __syncthreads();
    if (t < 512)
      Sbuf[t] = redf[((t >> 6) * 2) * 64 + (t & 63)] +
                redf[((t >> 6) * 2 + 1) * 64 + (t & 63)];
    __syncthreads();
#pragma unroll
    for (int j = 0; j < 4; ++j) {
      const int col = wn + j * 16 + r16;
      const float bv = b1[col];
      const float Sv = Sbuf[col];
#pragma unroll
      for (int i = 0; i < 4; ++i)
#pragma unroll
        for (int r = 0; r < 4; ++r) {
          const int row = wm + i * 16 + q * 4 + r;
          const float v = fmaxf((Sv + acc[i][j][r]) * (1.0f / 129.0f) + bv, 0.0f);
          const float o = __shfl_xor(v, 1, 64);
          if ((r16 & 1) == 0) {
            const int sl = (col >> 3) ^ (row & 7);
            *(unsigned int*)(void*)(smem + row * 512 + sl * 8 + (col & 7)) = pack2_bf16(v, o);
          }
        }
    }
  } else {
#pragma unroll
    for (int j = 0; j < 4; ++j) {
      const int col = wn + j * 16 + r16;
      const float bv = b1[col];
#pragma unroll
      for (int i = 0; i < 4; ++i)
#pragma unroll
        for (int r = 0; r < 4; ++r) {
          const int row = wm + i * 16 + q * 4 + r;
          const float v = fmaxf(acc[i][j][r] + bv, 0.0f);
          const float o = __shfl_xor(v, 1, 64);
          if ((r16 & 1) == 0) {
            const int sl = (col >> 3) ^ (row & 7);
            *(unsigned int*)(void*)(smem + row * 512 + sl * 8 + (col & 7)) = pack2_bf16(v, o);
          }
        }
    }
  }

#pragma unroll
  for (int i = 0; i < 4; ++i)
#pragma unroll
    for (int j = 0; j < 4; ++j)
      acc[i][j] = (f32x4)0.0f;

  for (int kt = 0; kt < 16; ++kt) {
    __syncthreads();
    gload_lds16(g2b1 + kt * 32, smem + 73728 + wave * 512);
    if (wave < 8) {
      short8 af[4], bfr[4];
#pragma unroll
      for (int i = 0; i < 4; ++i) {
        const int row = wm + i * 16 + r16;
        const int sl  = (kt * 4 + q) ^ (row & 7);
        af[i] = *(const short8*)(const void*)(smem + row * 512 + sl * 8);
      }
#pragma unroll
      for (int j = 0; j < 4; ++j) {
        const int row = wn + j * 16 + r16;
        const int c   = (q ^ ((row >> 1) & 3)) << 3;
        bfr[j] = *(const short8*)(const void*)(smem + 65536 + row * 32 + c);
      }
      __builtin_amdgcn_s_setprio(1);
#pragma unroll
      for (int i = 0; i < 4; ++i)
#pragma unroll
        for (int j = 0; j < 4; ++j)
          acc[i][j] = __builtin_amdgcn_mfma_f32_16x16x32_bf16(af[i], bfr[j], acc[i][j], 0, 0, 0);
      __builtin_amdgcn_s_setprio(0);
    }
    __syncthreads();
    if (kt < 15)
      gload_lds16(g2b0 + (kt + 1) * 32, smem + 65536 + wave * 512);
    if (wave >= 8) {
      short8 af[4], bfr[4];
#pragma unroll
      for (int i = 0; i < 4; ++i) {
        const int row = wm + i * 16 + r16;
        const int sl  = (kt * 4 + q) ^ (row & 7);
        af[i] = *(const short8*)(const void*)(smem + row * 512 + sl * 8);
      }
#pragma unroll
      for (int j = 0; j < 4; ++j) {
        const int row = wn + j * 16 + r16;
        const int c   = (q ^ ((row >> 1) & 3)) << 3;
        bfr[j] = *(const short8*)(const void*)(smem + 65536 + row * 32 + c);
      }
      __builtin_amdgcn_s_setprio(1);
#pragma unroll
      for (int i = 0; i < 4; ++i)
#pragma unroll
        for (int j = 0; j < 4; ++j)
          acc[i][j] = __builtin_amdgcn_mfma_f32_16x16x32_bf16(af[i], bfr[j], acc[i][j], 0, 0, 0);
      __builtin_amdgcn_s_setprio(0);
    }
  }
  __syncthreads();

  float pj[4];
  if (g == 0) {
    float sj[4];
#pragma unroll
    for (int j = 0; j < 4; ++j) {
      float a = 0.0f;
#pragma unroll
      for (int i = 0; i < 4; ++i)
#pragma unroll
        for (int r = 0; r < 4; ++r)
          a += acc[i][j][r];
      a += __shfl_xor(a, 16, 64);
      a += __shfl_xor(a, 32, 64);
      sj[j] = a;
    }
    if (q == 0) {
#pragma unroll
      for (int j = 0; j < 4; ++j) redf[wave * 64 + j * 16 + r16] = sj[j];
    }
    __syncthreads();
    if (t < 512)
      Sbuf[t] = redf[((t >> 6) * 2) * 64 + (t & 63)] +
                redf[((t >> 6) * 2 + 1) * 64 + (t & 63)];
    __syncthreads();
#pragma unroll
    for (int j = 0; j < 4; ++j) {
      const float bv = b2[wn + j * 16 + r16];
      const float Sv = Sbuf[wn + j * 16 + r16];
      float a = 0.0f;
#pragma unroll
      for (int i = 0; i < 4; ++i)
#pragma unroll
        for (int r = 0; r < 4; ++r)
          a += fmaxf((Sv + acc[i][j][r]) * (1.0f / 129.0f) + bv, 0.0f);
      a += __shfl_xor(a, 16, 64);
      a += __shfl_xor(a, 32, 64);
      pj[j] = a;
    }
  } else {
#pragma unroll
    for (int j = 0; j < 4; ++j) {
      const float bv = b2[wn + j * 16 + r16];
      float a = 0.0f;
#pragma unroll
      for (int i = 0; i < 4; ++i)
#pragma unroll
        for (int r = 0; r < 4; ++r)
          a += fmaxf(acc[i][j][r] + bv, 0.0f);
      a += __shfl_xor(a, 16, 64);
      a += __shfl_xor(a, 32, 64);
      pj[j] = a;
    }
  }
  if (q == 0) {
#pragma unroll
    for (int j = 0; j < 4; ++j) redf[wave * 64 + j * 16 + r16] = pj[j];
  }
  __syncthreads();
  if (t < 512)
    Sbuf[t] =
        (redf[((t >> 6) * 2) * 64 + (t & 63)] +
         redf[((t >> 6) * 2 + 1) * 64 + (t & 63)]) * (1.0f / 128.0f);
  __syncthreads();

  if (wave < 10) {
    float s = 0.0f;
    for (int c = l; c < 512; c += 64) s += Sbuf[c] * Wf[c * 10 + wave];
#pragma unroll
    for (int off = 32; off; off >>= 1) s += __shfl_down(s, off, 64);
    if (l == 0) out[(size_t)g * 10 + wave] = s + bfv[wave];
  }
}

// prep: blocks 0..511 transpose W1/W2 -> bf16 [n][k]; blocks 512..1023 fold
__global__ __launch_bounds__(1024) void prep(
    const float* __restrict__ W1, const float* __restrict__ W2,
    unsigned short* __restrict__ W1t, unsigned short* __restrict__ W2t,
    const float* __restrict__ W3, const float* __restrict__ Wlin,
    const float* __restrict__ b3, const float* __restrict__ blin,
    float* __restrict__ Wf, float* __restrict__ bfv) {
  const int b = blockIdx.x;
  if (b < 512) {
    __shared__ float tile[32][33];
    const int z  = b >> 8;
    const int by = (b >> 4) & 15;
    const int bx = b & 15;
    const float* W = z ? W2 : W1;
    unsigned short* Wt = z ? W2t : W1t;
    const int tx = threadIdx.x & 31;
    const int ty = threadIdx.x >> 5;
    tile[ty][tx] = W[(by * 32 + ty) * 512 + bx * 32 + tx];
    __syncthreads();
    Wt[(bx * 32 + ty) * 512 + by * 32 + tx] = bf16_rne(tile[tx][ty]);
  } else {
    const int c = b - 512;
    const int l = threadIdx.x;
    if (l < 64) {
      float acc[10];
#pragma unroll
      for (int o = 0; o < 10; ++o) acc[o] = 0.0f;
      for (int n = l; n < 512; n += 64) {
        const float wv = W3[c * 512 + n];
#pragma unroll
        for (int o = 0; o < 10; ++o) acc[o] += wv * Wlin[n * 10 + o];
      }
#pragma unroll
      for (int off = 32; off; off >>= 1)
#pragma unroll
        for (int o = 0; o < 10; ++o) acc[o] += __shfl_down(acc[o], off, 64);
      if (l == 0) {
#pragma unroll
        for (int o = 0; o < 10; ++o) Wf[c * 10 + o] = acc[o];
      }
      if (c < 10) {
        float s = 0.0f;
        for (int k = l; k < 512; k += 64) s += b3[k] * Wlin[k * 10 + c];
#pragma unroll
        for (int off = 32; off; off >>= 1) s += __shfl_down(s, off, 64);
        if (l == 0) bfv[c] = s + blin[c];
      }
    }
  }
}

extern "C" void kernel_launch(void* const* d_in, const int* in_sizes, int n_in,
                              void* d_out, int out_size, void* d_ws, size_t ws_size,
                              hipStream_t stream) {
  const float* x    = (const float*)d_in[0];
  const float* W1   = (const float*)d_in[1];
  const float* b1   = (const float*)d_in[2];
  const float* W2   = (const float*)d_in[3];
  const float* b2   = (const float*)d_in[4];
  const float* W3   = (const float*)d_in[5];
  const float* b3   = (const float*)d_in[6];
  const float* Wlin = (const float*)d_in[7];
  const float* blin = (const float*)d_in[8];
  float* out = (float*)d_out;

  char* ws = (char*)d_ws;
  unsigned short* W1t = (unsigned short*)ws;                 // 512 KB
  unsigned short* W2t = W1t + 512 * 512;                     // 512 KB
  float* Wf           = (float*)(W2t + 512 * 512);           // 20 KB
  float* bfv          = Wf + 512 * 10;                       // 40 B
  float* P            = bfv + 16;                            // 1 MB
  unsigned short* H1  = (unsigned short*)(P + 512 * 512);    // 64 MB

  const size_t need = (size_t)(W2t + 512 * 512 - W1t) * 2 +  // transposes
                      (512 * 10 + 16 + 512 * 512) * 4 +      // Wf,bfv,P
                      (size_t)65536 * 512 * 2;               // H1

  prep<<<1024, 1024, 0, stream>>>(W1, W2, W1t, W2t, W3, Wlin, b3, blin, Wf, bfv);

  if (ws_size >= need) {
    gemm1<<<1024, 512, 0, stream>>>(
        x, (const __hip_bfloat16*)W1t, b1, H1);
    gemm2<<<1024, 512, 0, stream>>>(
        H1, (const __hip_bfloat16*)W2t, b2, P);
    final_out<<<512, 64, 0, stream>>>(P, Wf, bfv, out);
  } else {
    fused_gcn<<<512, 1024, 0, stream>>>(
        x, (const __hip_bfloat16*)W1t, (const __hip_bfloat16*)W2t, b1, b2, Wf, bfv, out);
  }
}

// Round 4
// 297.196 us; speedup vs baseline: 1.0793x; 1.0793x over previous
//
#include <hip/hip_runtime.h>
#include <hip/hip_bf16.h>

// GCN_simple: B=512 graphs x 128 nodes, FEAT=HID=512, OUT=10.
// R12: split design, gemm1 made structurally IDENTICAL to the proven-fast
// gemm2 (~20us): x is pre-converted to bf16 (xb) inside prep (same RNE
// rounding as before -> identical numerics), so gemm1 stages A via
// global_load_lds DMA exactly like gemm2 instead of the latency-exposed
// f32-reg+pack+ds_write path (R11 gemm1: 128us, MfmaUtil 10%, 1.7TB/s).
// H1 epilogue write reordered (i,r outer, j inner) so each 128B line is
// completed by 4 consecutive 32B stores -> kills the 2.1x write
// amplification seen in R11 (WRITE_SIZE 137MB for a 64MB H1).
// Dispatches: prep(+conv) -> gemm1 -> gemm2 -> final_out.
// Fallback: R9 fused kernel if ws_size can't hold xb+H1 (~131MB).

typedef __attribute__((ext_vector_type(8))) short short8;
typedef __attribute__((ext_vector_type(4))) float f32x4;
typedef __attribute__((ext_vector_type(2))) unsigned int uint2v;

#define AS_G __attribute__((address_space(1)))
#define AS_L __attribute__((address_space(3)))

__device__ __forceinline__ void gload_lds16(const void* g, void* l) {
  __builtin_amdgcn_global_load_lds((const AS_G void*)g, (AS_L void*)l, 16, 0, 0);
}

// RNE fp32->bf16 (finite), packed: b -> high 16, a -> low 16.
__device__ __forceinline__ unsigned int pack2_bf16(float a, float b) {
  unsigned int ua = __float_as_uint(a);
  unsigned int ub = __float_as_uint(b);
  ua += 0x7FFFu + ((ua >> 16) & 1u);
  ub += 0x7FFFu + ((ub >> 16) & 1u);
  return (ua >> 16) | (ub & 0xFFFF0000u);
}

__device__ __forceinline__ unsigned short bf16_rne(float a) {
  unsigned int ua = __float_as_uint(a);
  ua += 0x7FFFu + ((ua >> 16) & 1u);
  return (unsigned short)(ua >> 16);
}

// ---------------------------------------------------------------------------
// gemm1: H1 = relu(agg(xb @ W1) + b1), bf16 out. Grid 1024 = 512 graphs x 2
// col-halves. Block 512 thr / 8 waves, tile 128x256, K=512 in 16 steps of 32.
// A (xb bf16) and B (W1t bf16) both staged via gload_lds dbuf (gemm2 clone).
// ---------------------------------------------------------------------------
__global__ __launch_bounds__(512, 4) void gemm1(
    const unsigned short* __restrict__ xb,    // [65536][512] bf16
    const __hip_bfloat16* __restrict__ W1t,   // [n][k] bf16
    const float* __restrict__ b1,
    unsigned short* __restrict__ H1)          // [65536][512] bf16
{
  __shared__ __align__(16) __hip_bfloat16 smem[26368];

  const int t    = threadIdx.x;
  const int orig = blockIdx.x;
  const int wgid = (orig & 7) * 128 + (orig >> 3);   // XCD-chunked (1024%8==0)
  const int g    = wgid >> 1;          // graph / M-tile
  const int nb   = wgid & 1;           // col half (256 cols)

  const int wave = t >> 6;
  const int l    = t & 63;
  const int q    = l >> 4;
  const int r16  = l & 15;
  const int wm   = (wave & 1) * 64;
  const int wn   = (wave >> 1) * 64;   // 0,64,128,192

  // A staging (1 gload_lds/thread): u = t -> (arow = t>>2, slot = t&3)
  const int arow = t >> 2;
  const int slot = t & 3;
  const unsigned short* gaA = xb + (size_t)(g * 128 + arow) * 512 +
                              ((slot ^ ((arow >> 1) & 3)) << 3);
  // B staging (2 issues)
  const int nrow0 = t >> 2;
  const int nrow1 = 128 + (t >> 2);
  const __hip_bfloat16* gb0 = W1t + (size_t)(nb * 256 + nrow0) * 512 +
                              ((slot ^ ((nrow0 >> 1) & 3)) << 3);
  const __hip_bfloat16* gb1 = W1t + (size_t)(nb * 256 + nrow1) * 512 +
                              ((slot ^ ((nrow1 >> 1) & 3)) << 3);

  f32x4 acc[4][4];
#pragma unroll
  for (int i = 0; i < 4; ++i)
#pragma unroll
    for (int j = 0; j < 4; ++j)
      acc[i][j] = (f32x4)0.0f;

  // prologue: stage kt=0
  gload_lds16(gaA, smem + wave * 512);
  gload_lds16(gb0, smem + 8192 + wave * 512);
  gload_lds16(gb1, smem + 8192 + 4096 + wave * 512);

  for (int kt = 0; kt < 16; ++kt) {
    const int cur = kt & 1;
    const int nxt = cur ^ 1;
    __syncthreads();

    if (kt < 15) {
      const int ko = (kt + 1) * 32;
      gload_lds16(gaA + ko, smem + nxt * 4096 + wave * 512);
      gload_lds16(gb0 + ko, smem + 8192 + nxt * 8192 + wave * 512);
      gload_lds16(gb1 + ko, smem + 8192 + nxt * 8192 + 4096 + wave * 512);
    }

    short8 af[4], bfr[4];
#pragma unroll
    for (int i = 0; i < 4; ++i) {
      const int row = wm + i * 16 + r16;
      const int c   = (q ^ ((row >> 1) & 3)) << 3;
      af[i] = *(const short8*)(const void*)(smem + cur * 4096 + row * 32 + c);
    }
#pragma unroll
    for (int j = 0; j < 4; ++j) {
      const int row = wn + j * 16 + r16;
      const int c   = (q ^ ((row >> 1) & 3)) << 3;
      bfr[j] = *(const short8*)(const void*)(smem + 8192 + cur * 8192 + row * 32 + c);
    }
    __builtin_amdgcn_s_setprio(1);
#pragma unroll
    for (int i = 0; i < 4; ++i)
#pragma unroll
      for (int j = 0; j < 4; ++j)
        acc[i][j] = __builtin_amdgcn_mfma_f32_16x16x32_bf16(af[i], bfr[j], acc[i][j], 0, 0, 0);
    __builtin_amdgcn_s_setprio(0);
  }

  float* redf = (float*)(smem + 24576);   // 8*64 f32
  float* Sbuf = (float*)(smem + 25600);   // 256 f32
  const size_t hbase = (size_t)g * 128 * 512 + nb * 256;

  if (g == 0) {
    // column sums over all 128 rows (this block owns all of graph 0's rows)
    float sj[4];
#pragma unroll
    for (int j = 0; j < 4; ++j) {
      float a = 0.0f;
#pragma unroll
      for (int i = 0; i < 4; ++i)
#pragma unroll
        for (int r = 0; r < 4; ++r)
          a += acc[i][j][r];
      a += __shfl_xor(a, 16, 64);
      a += __shfl_xor(a, 32, 64);
      sj[j] = a;
    }
    __syncthreads();
    if (q == 0) {
#pragma unroll
      for (int j = 0; j < 4; ++j) redf[wave * 64 + j * 16 + r16] = sj[j];
    }
    __syncthreads();
    if (t < 256)
      Sbuf[t] = redf[(2 * (t >> 6)) * 64 + (t & 63)] +
                redf[(2 * (t >> 6) + 1) * 64 + (t & 63)];
    __syncthreads();
    float bvv[4], Svv[4];
#pragma unroll
    for (int j = 0; j < 4; ++j) {
      bvv[j] = b1[nb * 256 + wn + j * 16 + r16];
      Svv[j] = Sbuf[wn + j * 16 + r16];
    }
#pragma unroll
    for (int i = 0; i < 4; ++i)
#pragma unroll
      for (int r = 0; r < 4; ++r) {
        const int row = wm + i * 16 + q * 4 + r;
#pragma unroll
        for (int j = 0; j < 4; ++j) {
          const float v = fmaxf((Svv[j] + acc[i][j][r]) * (1.0f / 129.0f) + bvv[j], 0.0f);
          const float o = __shfl_xor(v, 1, 64);
          if ((r16 & 1) == 0)
            *(unsigned int*)(void*)(H1 + hbase + (size_t)row * 512 + wn + j * 16 + r16) =
                pack2_bf16(v, o);
        }
      }
  } else {
    float bvv[4];
#pragma unroll
    for (int j = 0; j < 4; ++j) bvv[j] = b1[nb * 256 + wn + j * 16 + r16];
#pragma unroll
    for (int i = 0; i < 4; ++i)
#pragma unroll
      for (int r = 0; r < 4; ++r) {
        const int row = wm + i * 16 + q * 4 + r;
#pragma unroll
        for (int j = 0; j < 4; ++j) {
          const float v = fmaxf(acc[i][j][r] + bvv[j], 0.0f);
          const float o = __shfl_xor(v, 1, 64);
          if ((r16 & 1) == 0)
            *(unsigned int*)(void*)(H1 + hbase + (size_t)row * 512 + wn + j * 16 + r16) =
                pack2_bf16(v, o);
        }
      }
  }
}

// ---------------------------------------------------------------------------
// gemm2: C2 = H1 @ W2; P[g][c] = (1/128) * sum_rows relu(agg(C2) + b2).
// Same geometry as gemm1; epilogue pools instead of writing H-matrix.
// ---------------------------------------------------------------------------
__global__ __launch_bounds__(512, 4) void gemm2(
    const unsigned short* __restrict__ H1,    // [65536][512] bf16
    const __hip_bfloat16* __restrict__ W2t,   // [n][k] bf16
    const float* __restrict__ b2,
    float* __restrict__ P)                    // [512][512] f32 (mean-pooled)
{
  __shared__ __align__(16) __hip_bfloat16 smem[26368];

  const int t    = threadIdx.x;
  const int orig = blockIdx.x;
  const int wgid = (orig & 7) * 128 + (orig >> 3);
  const int g    = wgid >> 1;
  const int nb   = wgid & 1;

  const int wave = t >> 6;
  const int l    = t & 63;
  const int q    = l >> 4;
  const int r16  = l & 15;
  const int wm   = (wave & 1) * 64;
  const int wn   = (wave >> 1) * 64;

  const int arow = t >> 2;
  const int slot = t & 3;
  const unsigned short* gaA = H1 + (size_t)(g * 128 + arow) * 512 +
                              ((slot ^ ((arow >> 1) & 3)) << 3);
  const int nrow0 = t >> 2;
  const int nrow1 = 128 + (t >> 2);
  const __hip_bfloat16* gb0 = W2t + (size_t)(nb * 256 + nrow0) * 512 +
                              ((slot ^ ((nrow0 >> 1) & 3)) << 3);
  const __hip_bfloat16* gb1 = W2t + (size_t)(nb * 256 + nrow1) * 512 +
                              ((slot ^ ((nrow1 >> 1) & 3)) << 3);

  f32x4 acc[4][4];
#pragma unroll
  for (int i = 0; i < 4; ++i)
#pragma unroll
    for (int j = 0; j < 4; ++j)
      acc[i][j] = (f32x4)0.0f;

  gload_lds16(gaA, smem + wave * 512);
  gload_lds16(gb0, smem + 8192 + wave * 512);
  gload_lds16(gb1, smem + 8192 + 4096 + wave * 512);

  for (int kt = 0; kt < 16; ++kt) {
    const int cur = kt & 1;
    const int nxt = cur ^ 1;
    __syncthreads();

    if (kt < 15) {
      const int ko = (kt + 1) * 32;
      gload_lds16(gaA + ko, smem + nxt * 4096 + wave * 512);
      gload_lds16(gb0 + ko, smem + 8192 + nxt * 8192 + wave * 512);
      gload_lds16(gb1 + ko, smem + 8192 + nxt * 8192 + 4096 + wave * 512);
    }

    short8 af[4], bfr[4];
#pragma unroll
    for (int i = 0; i < 4; ++i) {
      const int row = wm + i * 16 + r16;
      const int c   = (q ^ ((row >> 1) & 3)) << 3;
      af[i] = *(const short8*)(const void*)(smem + cur * 4096 + row * 32 + c);
    }
#pragma unroll
    for (int j = 0; j < 4; ++j) {
      const int row = wn + j * 16 + r16;
      const int c   = (q ^ ((row >> 1) & 3)) << 3;
      bfr[j] = *(const short8*)(const void*)(smem + 8192 + cur * 8192 + row * 32 + c);
    }
    __builtin_amdgcn_s_setprio(1);
#pragma unroll
    for (int i = 0; i < 4; ++i)
#pragma unroll
      for (int j = 0; j < 4; ++j)
        acc[i][j] = __builtin_amdgcn_mfma_f32_16x16x32_bf16(af[i], bfr[j], acc[i][j], 0, 0, 0);
    __builtin_amdgcn_s_setprio(0);
  }

  float* redf = (float*)(smem + 24576);   // 8*64 f32
  float* Sbuf = (float*)(smem + 25600);   // 256 f32

  float pj[4];
  if (g == 0) {
    float sj[4];
#pragma unroll
    for (int j = 0; j < 4; ++j) {
      float a = 0.0f;
#pragma unroll
      for (int i = 0; i < 4; ++i)
#pragma unroll
        for (int r = 0; r < 4; ++r)
          a += acc[i][j][r];
      a += __shfl_xor(a, 16, 64);
      a += __shfl_xor(a, 32, 64);
      sj[j] = a;
    }
    __syncthreads();
    if (q == 0) {
#pragma unroll
      for (int j = 0; j < 4; ++j) redf[wave * 64 + j * 16 + r16] = sj[j];
    }
    __syncthreads();
    if (t < 256)
      Sbuf[t] = redf[(2 * (t >> 6)) * 64 + (t & 63)] +
                redf[(2 * (t >> 6) + 1) * 64 + (t & 63)];
    __syncthreads();
#pragma unroll
    for (int j = 0; j < 4; ++j) {
      const int col = wn + j * 16 + r16;
      const float bv = b2[nb * 256 + col];
      const float Sv = Sbuf[col];
      float a = 0.0f;
#pragma unroll
      for (int i = 0; i < 4; ++i)
#pragma unroll
        for (int r = 0; r < 4; ++r)
          a += fmaxf((Sv + acc[i][j][r]) * (1.0f / 129.0f) + bv, 0.0f);
      a += __shfl_xor(a, 16, 64);
      a += __shfl_xor(a, 32, 64);
      pj[j] = a;
    }
    __syncthreads();   // Sbuf/redf reads done before redf reuse below
  } else {
#pragma unroll
    for (int j = 0; j < 4; ++j) {
      const float bv = b2[nb * 256 + wn + j * 16 + r16];
      float a = 0.0f;
#pragma unroll
      for (int i = 0; i < 4; ++i)
#pragma unroll
        for (int r = 0; r < 4; ++r)
          a += fmaxf(acc[i][j][r] + bv, 0.0f);
      a += __shfl_xor(a, 16, 64);
      a += __shfl_xor(a, 32, 64);
      pj[j] = a;
    }
    __syncthreads();
  }
  if (q == 0) {
#pragma unroll
    for (int j = 0; j < 4; ++j) redf[wave * 64 + j * 16 + r16] = pj[j];
  }
  __syncthreads();
  if (t < 256)
    P[(size_t)g * 512 + nb * 256 + t] =
        (redf[(2 * (t >> 6)) * 64 + (t & 63)] +
         redf[(2 * (t >> 6) + 1) * 64 + (t & 63)]) * (1.0f / 128.0f);
}

// out[m][:] = P[m][:] @ Wf + bfv
__global__ void final_out(const float* __restrict__ P,
                          const float* __restrict__ Wf,
                          const float* __restrict__ bfv,
                          float* __restrict__ out) {
  const int m = blockIdx.x;
  const int l = threadIdx.x;
  float acc[10];
#pragma unroll
  for (int o = 0; o < 10; ++o) acc[o] = 0.0f;
  for (int c = l; c < 512; c += 64) {
    const float p = P[m * 512 + c];
#pragma unroll
    for (int o = 0; o < 10; ++o) acc[o] += p * Wf[c * 10 + o];
  }
#pragma unroll
  for (int off = 32; off; off >>= 1)
#pragma unroll
    for (int o = 0; o < 10; ++o) acc[o] += __shfl_down(acc[o], off, 64);
  if (l == 0) {
#pragma unroll
    for (int o = 0; o < 10; ++o) out[m * 10 + o] = acc[o] + bfv[o];
  }
}

// ===========================================================================
// R9 fused kernel (verified) — fallback when workspace can't hold xb+H1.
// ===========================================================================
__global__ __launch_bounds__(1024) void fused_gcn(
    const float* __restrict__ x,
    const __hip_bfloat16* __restrict__ W1t,
    const __hip_bfloat16* __restrict__ W2t,
    const float* __restrict__ b1,
    const float* __restrict__ b2,
    const float* __restrict__ Wf,
    const float* __restrict__ bfv,
    float* __restrict__ out)
{
  __shared__ __align__(16) __hip_bfloat16 smem[81920];

  const int t  = threadIdx.x;
  const int g  = blockIdx.x;
  const int wave = t >> 6;
  const int l    = t & 63;
  const int q    = l >> 4;
  const int r16  = l & 15;
  const int wm   = (wave & 1) * 64;
  const int wn   = (wave >> 1) * 64;

  const int arow = t >> 3;
  const int kq   = t & 7;
  const float* ga = x + ((size_t)g * 128 + arow) * 512 + kq * 4;
  const int awoff = arow * 32 + (((kq >> 1) ^ ((arow >> 1) & 3)) << 3) + (kq & 1) * 4;

  const int brow = t >> 2;
  const int bgc  = (t & 3) ^ ((brow >> 1) & 3);
  const size_t boff = (size_t)brow * 512 + bgc * 8;
  const __hip_bfloat16* g1b0 = W1t + boff;
  const __hip_bfloat16* g1b1 = g1b0 + (size_t)256 * 512;

  f32x4 acc[4][4];
#pragma unroll
  for (int i = 0; i < 4; ++i)
#pragma unroll
    for (int j = 0; j < 4; ++j)
      acc[i][j] = (f32x4)0.0f;

  {
    f32x4 a0 = *(const f32x4*)(const void*)ga;
    gload_lds16(g1b0, smem + 49152 + wave * 512);
    gload_lds16(g1b1, smem + 49152 + 8192 + wave * 512);
    uint2v w;
    w[0] = pack2_bf16(a0[0], a0[1]);
    w[1] = pack2_bf16(a0[2], a0[3]);
    *(uint2v*)(void*)(smem + awoff) = w;
  }
  for (int kt = 0; kt < 16; ++kt) {
    const int cur = kt & 1;
    const int nxt = cur ^ 1;
    __syncthreads();

    f32x4 aN;
    if (kt < 15) {
      const int ko = (kt + 1) * 32;
      aN = *(const f32x4*)(const void*)(ga + ko);
      gload_lds16(g1b0 + ko, smem + 49152 + nxt * 16384 + wave * 512);
      gload_lds16(g1b1 + ko, smem + 49152 + nxt * 16384 + 8192 + wave * 512);
    }

    short8 af[4], bfr[4];
#pragma unroll
    for (int i = 0; i < 4; ++i) {
      const int row = wm + i * 16 + r16;
      const int c   = (q ^ ((row >> 1) & 3)) << 3;
      af[i] = *(const short8*)(const void*)(smem + cur * 4096 + row * 32 + c);
    }
#pragma unroll
    for (int j = 0; j < 4; ++j) {
      const int row = wn + j * 16 + r16;
      const int c   = (q ^ ((row >> 1) & 3)) << 3;
      bfr[j] = *(const short8*)(const void*)(smem + 49152 + cur * 16384 + row * 32 + c);
    }
#pragma unroll
    for (int i = 0; i < 4; ++i)
#pragma unroll
      for (int j = 0; j < 4; ++j)
        acc[i][j] = __builtin_amdgcn_mfma_f32_16x16x32_bf16(af[i], bfr[j], acc[i][j], 0, 0, 0);

    if (kt < 15) {
      uint2v w;
      w[0] = pack2_bf16(aN[0], aN[1]);
      w[1] = pack2_bf16(aN[2], aN[3]);
      *(uint2v*)(void*)(smem + nxt * 4096 + awoff) = w;
    }
  }
  __syncthreads();

  const __hip_bfloat16* g2b0 = W2t + boff;
  const __hip_bfloat16* g2b1 = g2b0 + (size_t)256 * 512;
  gload_lds16(g2b0, smem + 65536 + wave * 512);

  float* redf = (float*)(smem + 73728);
  float* Sbuf = (float*)(smem + 75776);

  if (g == 0) {
    float sj[4];
#pragma unroll
    for (int j = 0; j < 4; ++j) {
      float a = 0.0f;
#pragma unroll
      for (int i = 0; i < 4; ++i)
#pragma unroll
        for (int r = 0; r < 4; ++r)
          a += acc[i][j][r];
      a += __shfl_xor(a, 16, 64);
      a += __shfl_xor(a, 32, 64);
      sj[j] = a;
    }
    if (q == 0) {
#pragma unroll
      for (int j = 0; j < 4; ++j) redf[wave * 64 + j * 16 + r16] = sj[j];
    }
    __syncthreads();
    if (t < 512)
      Sbuf[t] = redf[((t >> 6) * 2) * 64 + (t & 63)] +
                redf[((t >> 6) * 2 + 1) * 64 + (t & 63)];
    __syncthreads();
#pragma unroll
    for (int j = 0; j < 4; ++j) {
      const int col = wn + j * 16 + r16;
      const float bv = b1[col];
      const float Sv = Sbuf[col];
#pragma unroll
      for (int i = 0; i < 4; ++i)
#pragma unroll
        for (int r = 0; r < 4; ++r) {
          const int row = wm + i * 16 + q * 4 + r;
          const float v = fmaxf((Sv + acc[i][j][r]) * (1.0f / 129.0f) + bv, 0.0f);
          const float o = __shfl_xor(v, 1, 64);
          if ((r16 & 1) == 0) {
            const int sl = (col >> 3) ^ (row & 7);
            *(unsigned int*)(void*)(smem + row * 512 + sl * 8 + (col & 7)) = pack2_bf16(v, o);
          }
        }
    }
  } else {
#pragma unroll
    for (int j = 0; j < 4; ++j) {
      const int col = wn + j * 16 + r16;
      const float bv = b1[col];
#pragma unroll
      for (int i = 0; i < 4; ++i)
#pragma unroll
        for (int r = 0; r < 4; ++r) {
          const int row = wm + i * 16 + q * 4 + r;
          const float v = fmaxf(acc[i][j][r] + bv, 0.0f);
          const float o = __shfl_xor(v, 1, 64);
          if ((r16 & 1) == 0) {
            const int sl = (col >> 3) ^ (row & 7);
            *(unsigned int*)(void*)(smem + row * 512 + sl * 8 + (col & 7)) = pack2_bf16(v, o);
          }
        }
    }
  }

#pragma unroll
  for (int i = 0; i < 4; ++i)
#pragma unroll
    for (int j = 0; j < 4; ++j)
      acc[i][j] = (f32x4)0.0f;

  for (int kt = 0; kt < 16; ++kt) {
    __syncthreads();
    gload_lds16(g2b1 + kt * 32, smem + 73728 + wave * 512);
    if (wave < 8) {
      short8 af[4], bfr[4];
#pragma unroll
      for (int i = 0; i < 4; ++i) {
        const int row = wm + i * 16 + r16;
        const int sl  = (kt * 4 + q) ^ (row & 7);
        af[i] = *(const short8*)(const void*)(smem + row * 512 + sl * 8);
      }
#pragma unroll
      for (int j = 0; j < 4; ++j) {
        const int row = wn + j * 16 + r16;
        const int c   = (q ^ ((row >> 1) & 3)) << 3;
        bfr[j] = *(const short8*)(const void*)(smem + 65536 + row * 32 + c);
      }
      __builtin_amdgcn_s_setprio(1);
#pragma unroll
      for (int i = 0; i < 4; ++i)
#pragma unroll
        for (int j = 0; j < 4; ++j)
          acc[i][j] = __builtin_amdgcn_mfma_f32_16x16x32_bf16(af[i], bfr[j], acc[i][j], 0, 0, 0);
      __builtin_amdgcn_s_setprio(0);
    }
    __syncthreads();
    if (kt < 15)
      gload_lds16(g2b0 + (kt + 1) * 32, smem + 65536 + wave * 512);
    if (wave >= 8) {
      short8 af[4], bfr[4];
#pragma unroll
      for (int i = 0; i < 4; ++i) {
        const int row = wm + i * 16 + r16;
        const int sl  = (kt * 4 + q) ^ (row & 7);
        af[i] = *(const short8*)(const void*)(smem + row * 512 + sl * 8);
      }
#pragma unroll
      for (int j = 0; j < 4; ++j) {
        const int row = wn + j * 16 + r16;
        const int c   = (q ^ ((row >> 1) & 3)) << 3;
        bfr[j] = *(const short8*)(const void*)(smem + 65536 + row * 32 + c);
      }
      __builtin_amdgcn_s_setprio(1);
#pragma unroll
      for (int i = 0; i < 4; ++i)
#pragma unroll
        for (int j = 0; j < 4; ++j)
          acc[i][j] = __builtin_amdgcn_mfma_f32_16x16x32_bf16(af[i], bfr[j], acc[i][j], 0, 0, 0);
      __builtin_amdgcn_s_setprio(0);
    }
  }
  __syncthreads();

  float pj[4];
  if (g == 0) {
    float sj[4];
#pragma unroll
    for (int j = 0; j < 4; ++j) {
      float a = 0.0f;
#pragma unroll
      for (int i = 0; i < 4; ++i)
#pragma unroll
        for (int r = 0; r < 4; ++r)
          a += acc[i][j][r];
      a += __shfl_xor(a, 16, 64);
      a += __shfl_xor(a, 32, 64);
      sj[j] = a;
    }
    if (q == 0) {
#pragma unroll
      for (int j = 0; j < 4; ++j) redf[wave * 64 + j * 16 + r16] = sj[j];
    }
    __syncthreads();
    if (t < 512)
      Sbuf[t] = redf[((t >> 6) * 2) * 64 + (t & 63)] +
                redf[((t >> 6) * 2 + 1) * 64 + (t & 63)];
    __syncthreads();
#pragma unroll
    for (int j = 0; j < 4; ++j) {
      const float bv = b2[wn + j * 16 + r16];
      const float Sv = Sbuf[wn + j * 16 + r16];
      float a = 0.0f;
#pragma unroll
      for (int i = 0; i < 4; ++i)
#pragma unroll
        for (int r = 0; r < 4; ++r)
          a += fmaxf((Sv + acc[i][j][r]) * (1.0f / 129.0f) + bv, 0.0f);
      a += __shfl_xor(a, 16, 64);
      a += __shfl_xor(a, 32, 64);
      pj[j] = a;
    }
  } else {
#pragma unroll
    for (int j = 0; j < 4; ++j) {
      const float bv = b2[wn + j * 16 + r16];
      float a = 0.0f;
#pragma unroll
      for (int i = 0; i < 4; ++i)
#pragma unroll
        for (int r = 0; r < 4; ++r)
          a += fmaxf(acc[i][j][r] + bv, 0.0f);
      a += __shfl_xor(a, 16, 64);
      a += __shfl_xor(a, 32, 64);
      pj[j] = a;
    }
  }
  if (q == 0) {
#pragma unroll
    for (int j = 0; j < 4; ++j) redf[wave * 64 + j * 16 + r16] = pj[j];
  }
  __syncthreads();
  if (t < 512)
    Sbuf[t] =
        (redf[((t >> 6) * 2) * 64 + (t & 63)] +
         redf[((t >> 6) * 2 + 1) * 64 + (t & 63)]) * (1.0f / 128.0f);
  __syncthreads();

  if (wave < 10) {
    float s = 0.0f;
    for (int c = l; c < 512; c += 64) s += Sbuf[c] * Wf[c * 10 + wave];
#pragma unroll
    for (int off = 32; off; off >>= 1) s += __shfl_down(s, off, 64);
    if (l == 0) out[(size_t)g * 10 + wave] = s + bfv[wave];
  }
}

// prep: blocks 0..511 transpose W1/W2 -> bf16 [n][k]; blocks 512..1023 fold
// Wf = W3@Wlin, bfv = b3@Wlin + blin; blocks 1024.. convert x -> xb bf16.
__global__ __launch_bounds__(1024) void prep(
    const float* __restrict__ W1, const float* __restrict__ W2,
    unsigned short* __restrict__ W1t, unsigned short* __restrict__ W2t,
    const float* __restrict__ W3, const float* __restrict__ Wlin,
    const float* __restrict__ b3, const float* __restrict__ blin,
    float* __restrict__ Wf, float* __restrict__ bfv,
    const float* __restrict__ x, unsigned short* __restrict__ xb) {
  const int b = blockIdx.x;
  if (b < 512) {
    __shared__ float tile[32][33];
    const int z  = b >> 8;
    const int by = (b >> 4) & 15;
    const int bx = b & 15;
    const float* W = z ? W2 : W1;
    unsigned short* Wt = z ? W2t : W1t;
    const int tx = threadIdx.x & 31;
    const int ty = threadIdx.x >> 5;
    tile[ty][tx] = W[(by * 32 + ty) * 512 + bx * 32 + tx];
    __syncthreads();
    Wt[(bx * 32 + ty) * 512 + by * 32 + tx] = bf16_rne(tile[tx][ty]);
  } else if (b < 1024) {
    const int c = b - 512;
    const int l = threadIdx.x;
    if (l < 64) {
      float acc[10];
#pragma unroll
      for (int o = 0; o < 10; ++o) acc[o] = 0.0f;
      for (int n = l; n < 512; n += 64) {
        const float wv = W3[c * 512 + n];
#pragma unroll
        for (int o = 0; o < 10; ++o) acc[o] += wv * Wlin[n * 10 + o];
      }
#pragma unroll
      for (int off = 32; off; off >>= 1)
#pragma unroll
        for (int o = 0; o < 10; ++o) acc[o] += __shfl_down(acc[o], off, 64);
      if (l == 0) {
#pragma unroll
        for (int o = 0; o < 10; ++o) Wf[c * 10 + o] = acc[o];
      }
      if (c < 10) {
        float s = 0.0f;
        for (int k = l; k < 512; k += 64) s += b3[k] * Wlin[k * 10 + c];
#pragma unroll
        for (int off = 32; off; off >>= 1) s += __shfl_down(s, off, 64);
        if (l == 0) bfv[c] = s + blin[c];
      }
    }
  } else {
    // x -> xb (bf16 RNE), 8192 f32 per block, fully coalesced 16B/8B lanes
    const size_t base = (size_t)(b - 1024) * 8192;
    const int tt = threadIdx.x;
#pragma unroll
    for (int jj = 0; jj < 2; ++jj) {
      const size_t off = base + (size_t)jj * 4096 + (size_t)tt * 4;
      const f32x4 v = *(const f32x4*)(const void*)(x + off);
      uint2v w;
      w[0] = pack2_bf16(v[0], v[1]);
      w[1] = pack2_bf16(v[2], v[3]);
      *(uint2v*)(void*)(xb + off) = w;
    }
  }
}

extern "C" void kernel_launch(void* const* d_in, const int* in_sizes, int n_in,
                              void* d_out, int out_size, void* d_ws, size_t ws_size,
                              hipStream_t stream) {
  const float* x    = (const float*)d_in[0];
  const float* W1   = (const float*)d_in[1];
  const float* b1   = (const float*)d_in[2];
  const float* W2   = (const float*)d_in[3];
  const float* b2   = (const float*)d_in[4];
  const float* W3   = (const float*)d_in[5];
  const float* b3   = (const float*)d_in[6];
  const float* Wlin = (const float*)d_in[7];
  const float* blin = (const float*)d_in[8];
  float* out = (float*)d_out;

  char* ws = (char*)d_ws;
  unsigned short* W1t = (unsigned short*)ws;                 // 512 KB
  unsigned short* W2t = W1t + 512 * 512;                     // 512 KB
  float* Wf           = (float*)(W2t + 512 * 512);           // 20 KB
  float* bfv          = Wf + 512 * 10;                       // 64 B
  float* P            = bfv + 16;                            // 1 MB
  unsigned short* H1  = (unsigned short*)(P + 512 * 512);    // 64 MB
  unsigned short* xb  = H1 + (size_t)65536 * 512;            // 64 MB

  const size_t need = (size_t)512 * 512 * 2 * 2 +            // W1t, W2t
                      (512 * 10 + 16 + 512 * 512) * 4 +      // Wf, bfv, P
                      (size_t)65536 * 512 * 2 * 2;           // H1, xb

  const bool split = ws_size >= need;

  prep<<<split ? 5120 : 1024, 1024, 0, stream>>>(
      W1, W2, W1t, W2t, W3, Wlin, b3, blin, Wf, bfv, x, xb);

  if (split) {
    gemm1<<<1024, 512, 0, stream>>>(xb, (const __hip_bfloat16*)W1t, b1, H1);
    gemm2<<<1024, 512, 0, stream>>>(H1, (const __hip_bfloat16*)W2t, b2, P);
    final_out<<<512, 64, 0, stream>>>(P, Wf, bfv, out);
  } else {
    fused_gcn<<<512, 1024, 0, stream>>>(
        x, (const __hip_bfloat16*)W1t, (const __hip_bfloat16*)W2t, b1, b2, Wf, bfv, out);
  }
}